// Round 1
// baseline (338.687 us; speedup 1.0000x reference)
//
#include <hip/hip_runtime.h>
#include <hip/hip_bf16.h>

// Decoder_bipartite: out[e] = sigmoid( relu( [z_src[row[e]] ; z_dst[col[e]]] @ W1^T + b1 ) @ W2^T + b2 )
// H=128, K=2H=256, E=1e6. bf16 MFMA (16x16x32), fp32 accum.

#define H 128
#define K2 256
#define BM 128      // edges per tile
#define NW 4        // waves per block
#define WROWS 32    // edge-rows per wave

typedef __bf16 bf16x8 __attribute__((ext_vector_type(8)));
typedef float  f32x4  __attribute__((ext_vector_type(4)));

__device__ __forceinline__ bf16x8 cvt8(const float4 a, const float4 b) {
    bf16x8 r;
    r[0] = (__bf16)a.x; r[1] = (__bf16)a.y; r[2] = (__bf16)a.z; r[3] = (__bf16)a.w;
    r[4] = (__bf16)b.x; r[5] = (__bf16)b.y; r[6] = (__bf16)b.z; r[7] = (__bf16)b.w;
    return r;
}

__global__ __launch_bounds__(256, 2)
void decoder_kernel(const float* __restrict__ zsrc, const float* __restrict__ zdst,
                    const int* __restrict__ row, const int* __restrict__ col,
                    const float* __restrict__ W1, const float* __restrict__ b1,
                    const float* __restrict__ W2, const float* __restrict__ b2,
                    float* __restrict__ out, int E, int ntiles) {
    // W1^T packed in MFMA B-fragment order: slot = kb*8+nt, then lane, then 8 k-elems.
    __shared__ __bf16 sB[64 * 64 * 8];   // 64 KB

    const int tid  = threadIdx.x;
    const int lane = tid & 63;
    const int wave = tid >> 6;

    // ---- stage W1^T -> LDS (fragment-packed, conflict-free reads later) ----
    #pragma unroll
    for (int i = 0; i < 16; ++i) {
        int c    = tid + 256 * i;          // chunk 0..4095
        int cl   = c & 63;
        int slot = c >> 6;
        int kb   = slot >> 3, nt = slot & 7;
        int n    = nt * 16 + (cl & 15);
        int k0   = kb * 32 + ((cl >> 4) << 3);
        const float4* wp = reinterpret_cast<const float4*>(W1 + n * K2 + k0);
        float4 w0 = wp[0], w1 = wp[1];
        *reinterpret_cast<bf16x8*>(&sB[(size_t)c * 8]) = cvt8(w0, w1);
    }
    // per-lane epilogue constants: b1 / W2 slices for col = lane&15 of each n-tile
    float b1v[8], w2v[8];
    #pragma unroll
    for (int nt = 0; nt < 8; ++nt) {
        b1v[nt] = b1[nt * 16 + (lane & 15)];
        w2v[nt] = W2[nt * 16 + (lane & 15)];
    }
    const float bias2 = b2[0];
    __syncthreads();   // sB ready; no LDS writes after this -> no barriers in loop

    const int koff = (lane >> 4) << 3;     // 0,8,16,24: this lane's k-offset in a 32-k block

    for (int tile = blockIdx.x; tile < ntiles; tile += gridDim.x) {
        const int rbase = tile * BM + wave * WROWS;
        int e0 = rbase + (lane & 15);
        int e1 = e0 + 16;
        int e0c = e0 < E ? e0 : E - 1;
        int e1c = e1 < E ? e1 : E - 1;
        const float* a0s = zsrc + (size_t)row[e0c] * H;
        const float* a1s = zsrc + (size_t)row[e1c] * H;
        const float* a0d = zdst + (size_t)col[e0c] * H;
        const float* a1d = zdst + (size_t)col[e1c] * H;

        f32x4 zero = {0.f, 0.f, 0.f, 0.f};
        f32x4 acc[2][8];
        #pragma unroll
        for (int mt = 0; mt < 2; ++mt)
            #pragma unroll
            for (int nt = 0; nt < 8; ++nt)
                acc[mt][nt] = zero;

        #pragma unroll
        for (int kb = 0; kb < 8; ++kb) {
            const float* p0 = (kb < 4) ? a0s : a0d;
            const float* p1 = (kb < 4) ? a1s : a1d;
            const int ko = (kb & 3) * 32 + koff;
            const float4* q0 = reinterpret_cast<const float4*>(p0 + ko);
            const float4* q1 = reinterpret_cast<const float4*>(p1 + ko);
            bf16x8 afr0 = cvt8(q0[0], q0[1]);
            bf16x8 afr1 = cvt8(q1[0], q1[1]);
            #pragma unroll
            for (int nt = 0; nt < 8; ++nt) {
                bf16x8 bfr = *reinterpret_cast<const bf16x8*>(&sB[(size_t)((kb * 8 + nt) * 64 + lane) * 8]);
                acc[0][nt] = __builtin_amdgcn_mfma_f32_16x16x32_bf16(afr0, bfr, acc[0][nt], 0, 0, 0);
                acc[1][nt] = __builtin_amdgcn_mfma_f32_16x16x32_bf16(afr1, bfr, acc[1][nt], 0, 0, 0);
            }
        }

        // epilogue: +b1, ReLU, dot W2 across n (in-wave), +b2, sigmoid, store
        #pragma unroll
        for (int mt = 0; mt < 2; ++mt) {
            #pragma unroll
            for (int r = 0; r < 4; ++r) {
                float p = 0.f;
                #pragma unroll
                for (int nt = 0; nt < 8; ++nt) {
                    float h = acc[mt][nt][r] + b1v[nt];
                    h = h > 0.f ? h : 0.f;
                    p += h * w2v[nt];
                }
                p += __shfl_xor(p, 1);
                p += __shfl_xor(p, 2);
                p += __shfl_xor(p, 4);
                p += __shfl_xor(p, 8);
                int e = rbase + mt * 16 + ((lane >> 4) << 2) + r;
                if ((lane & 15) == 0 && e < E) {
                    float logit = p + bias2;
                    out[e] = 1.f / (1.f + __expf(-logit));
                }
            }
        }
    }
}

extern "C" void kernel_launch(void* const* d_in, const int* in_sizes, int n_in,
                              void* d_out, int out_size, void* d_ws, size_t ws_size,
                              hipStream_t stream) {
    const float* zsrc = (const float*)d_in[0];
    const float* zdst = (const float*)d_in[1];
    const int*   eli  = (const int*)d_in[2];   // [2,E] flat: row then col
    const float* W1   = (const float*)d_in[3];
    const float* b1   = (const float*)d_in[4];
    const float* W2   = (const float*)d_in[5];
    const float* b2   = (const float*)d_in[6];
    float* out = (float*)d_out;

    const int E = in_sizes[2] / 2;
    const int ntiles = (E + BM - 1) / BM;
    const int grid = ntiles < 1024 ? ntiles : 1024;

    decoder_kernel<<<grid, 256, 0, stream>>>(zsrc, zdst, eli, eli + E,
                                             W1, b1, W2, b2, out, E, ntiles);
}